// Round 2
// baseline (428.524 us; speedup 1.0000x reference)
//
#include <hip/hip_runtime.h>
#include <stdint.h>

#define BB 8
#define SS 2048
#define DD 1024
#define KREAL 204

typedef __attribute__((ext_vector_type(8))) short short8;
typedef __attribute__((ext_vector_type(4))) float floatx4;
typedef uint16_t u16;
typedef uint32_t u32;

__device__ __forceinline__ float bf2f(u16 u) {
    union { float f; u32 i; } c; c.i = ((u32)u) << 16; return c.f;
}
__device__ __forceinline__ u16 f2bf(float f) {
    union { float f; u32 i; } c; c.f = f;
    u32 i = c.i;
    u32 r = (i + 0x7FFFu + ((i >> 16) & 1u)) >> 16;
    return (u16)r;
}

#if defined(__has_builtin)
#if __has_builtin(__builtin_amdgcn_global_load_lds)
#define HAVE_GLL 1
#endif
#endif

__device__ __forceinline__ void gload16(const u16* g, u16* l) {
#ifdef HAVE_GLL
    __builtin_amdgcn_global_load_lds(
        (const __attribute__((address_space(1))) void*)(uintptr_t)g,
        (__attribute__((address_space(3))) void*)(u32)(uintptr_t)(void*)l,
        16, 0, 0);
#else
    *(uint4*)l = *(const uint4*)g;
#endif
}

#define VM_WAIT(N) asm volatile("s_waitcnt vmcnt(" #N ")" ::: "memory")
#define S_BAR()    asm volatile("s_barrier" ::: "memory")

// ===========================================================================
// Legacy 64-wide-row swizzled staging (kept for k_gemm64 only).
// ===========================================================================
__device__ __forceinline__ void stage64(const u16* __restrict__ src, size_t ld,
                                        u16* lds, int tid) {
#pragma unroll
    for (int j = 0; j < 2; j++) {
        int flat = j * 256 + tid;
        int row = flat >> 3, slot = flat & 7;
        int kg = slot ^ (row & 7);
        gload16(src + (size_t)row * ld + kg * 8, lds + flat * 8);
    }
}
__device__ __forceinline__ short8 frag(const u16* lds, int row, int kslot) {
    return *(const short8*)&lds[(row << 6) + (((kslot ^ (row & 7)) & 7) << 3)];
}

// ===========================================================================
// 256x256 8-phase GEMM core (8 waves, BK=64 split into two K-half planes of
// 32). LDS = 128 KiB. Staging via global_load_lds with pre-swizzled SOURCE
// (kg = slot ^ ((row>>1)&3)); frag reads apply the matching XOR -> max
// 2-way bank aliasing (free). Counted-vmcnt protocol (never 0 in main loop).
// Verified: SQ_LDS_BANK_CONFLICT == 0 (round 1).
// ===========================================================================
__device__ __forceinline__ short8 frag32(const u16* plane, int row, int ks) {
    return *(const short8*)&plane[(row << 5) + (((ks ^ ((row >> 1) & 3)) & 3) << 3)];
}

__device__ __forceinline__ void stage_half(const u16* s0, const u16* s1,
                                           u16* dp, int tid) {
    gload16(s0, dp + tid * 8);
    gload16(s1, dp + 4096 + tid * 8);
}

template <int MT, bool LOADB>
__device__ __forceinline__ void phase16(const u16* Apl, const u16* Bpl,
                                        int arow, int brow, int ln, int quad,
                                        short8 (&bv)[4], floatx4 (&acc)[8][4]) {
    short8 af[4];
#pragma unroll
    for (int i = 0; i < 4; i++) af[i] = frag32(Apl, arow + (MT + i) * 16 + ln, quad);
    if (LOADB) {
#pragma unroll
        for (int nt = 0; nt < 4; nt++) bv[nt] = frag32(Bpl, brow + nt * 16 + ln, quad);
    }
    __builtin_amdgcn_s_setprio(1);
#pragma unroll
    for (int i = 0; i < 4; i++)
#pragma unroll
        for (int nt = 0; nt < 4; nt++)
            acc[MT + i][nt] = __builtin_amdgcn_mfma_f32_16x16x32_bf16(
                af[i], bv[nt], acc[MT + i][nt], 0, 0, 0);
    __builtin_amdgcn_s_setprio(0);
}

template <int NT>
__device__ __forceinline__ void gemm_core256(
    const u16* __restrict__ Ag, size_t lda,
    const u16* __restrict__ Bg, size_t ldb,
    u16* lds, int tid, floatx4 (&acc)[8][4]) {
    const int lane = tid & 63, w = tid >> 6;
    const int arow = (w >> 2) * 128, brow = (w & 3) * 64;
    const int ln = lane & 15, quad = lane >> 4;
    const int srow = tid >> 2;
    const int kgp = (tid & 3) ^ ((srow >> 1) & 3);
    const u16* A0 = Ag + (size_t)srow * lda + kgp * 8;
    const u16* A1 = Ag + (size_t)(srow + 128) * lda + kgp * 8;
    const u16* B0 = Bg + (size_t)srow * ldb + kgp * 8;
    const u16* B1 = Bg + (size_t)(srow + 128) * ldb + kgp * 8;
    u16* Al = lds;
    u16* Bl = lds + 32768;

    // prologue: (0,Ak0)(0,Bk0)(0,Ak1)(0,Bk1)(1,Ak0)(1,Bk0) = 12 loads/thread
    stage_half(A0,      A1,      Al,         tid);
    stage_half(B0,      B1,      Bl,         tid);
    stage_half(A0 + 32, A1 + 32, Al + 8192,  tid);
    stage_half(B0 + 32, B1 + 32, Bl + 8192,  tid);
    stage_half(A0 + 64, A1 + 64, Al + 16384, tid);
    stage_half(B0 + 64, B1 + 64, Bl + 16384, tid);

    short8 bv[4];
#pragma unroll 2
    for (int t = 0; t < NT - 1; ++t) {
        const int p  = (t & 1) * 2;
        const int pn = 2 - p;
        const u16* Ap0 = Al + p * 8192;
        const u16* Ap1 = Al + p * 8192 + 8192;
        const u16* Bp0 = Bl + p * 8192;
        const u16* Bp1 = Bl + p * 8192 + 8192;
        const size_t o1 = (size_t)(t + 1) * 64;
        const size_t o2 = (size_t)(t + 2) * 64;
        VM_WAIT(8); S_BAR();
        stage_half(A0 + o1 + 32, A1 + o1 + 32, Al + (pn + 1) * 8192, tid);
        phase16<0, true >(Ap0, Bp0, arow, brow, ln, quad, bv, acc);
        stage_half(B0 + o1 + 32, B1 + o1 + 32, Bl + (pn + 1) * 8192, tid);
        phase16<4, false>(Ap0, Bp0, arow, brow, ln, quad, bv, acc);
        VM_WAIT(8); S_BAR();
        if (t + 2 < NT) stage_half(A0 + o2, A1 + o2, Al + p * 8192, tid);
        phase16<0, true >(Ap1, Bp1, arow, brow, ln, quad, bv, acc);
        if (t + 2 < NT) stage_half(B0 + o2, B1 + o2, Bl + p * 8192, tid);
        phase16<4, false>(Ap1, Bp1, arow, brow, ln, quad, bv, acc);
    }
    {   // peel t = NT-1: outstanding = {(t,Ak1),(t,Bk1)} = 4 loads
        const int p = ((NT - 1) & 1) * 2;
        const u16* Ap0 = Al + p * 8192;
        const u16* Ap1 = Al + p * 8192 + 8192;
        const u16* Bp0 = Bl + p * 8192;
        const u16* Bp1 = Bl + p * 8192 + 8192;
        VM_WAIT(4); S_BAR();
        phase16<0, true >(Ap0, Bp0, arow, brow, ln, quad, bv, acc);
        phase16<4, false>(Ap0, Bp0, arow, brow, ln, quad, bv, acc);
        VM_WAIT(0); S_BAR();
        phase16<0, true >(Ap1, Bp1, arow, brow, ln, quad, bv, acc);
        phase16<4, false>(Ap1, Bp1, arow, brow, ln, quad, bv, acc);
    }
}

// ===========================================================================
// Epilogue stores for the 256x256 tile (LDS bounce -> contiguous dwordx4).
// ===========================================================================
template <typename F>
__device__ __forceinline__ void store_rm256(u16* smem, u16* gbase, size_t ldc,
                                            int wm, int wn, int ln, int quad,
                                            int tid, F val) {
    for (int half = 0; half < 2; half++) {
        __syncthreads();
        if (wm == half) {
#pragma unroll
            for (int mt = 0; mt < 8; mt++)
#pragma unroll
                for (int nt = 0; nt < 4; nt++)
#pragma unroll
                    for (int r = 0; r < 4; r++)
                        smem[(mt * 16 + quad * 4 + r) * 264 + wn * 64 + nt * 16 + ln] =
                            val(mt, nt, r);
        }
        __syncthreads();
#pragma unroll
        for (int j = 0; j < 8; j++) {
            int flat = j * 512 + tid;
            int row = flat >> 5, c = flat & 31;
            *(uint4*)&gbase[(size_t)(half * 128 + row) * ldc + c * 8] =
                *(const uint4*)&smem[row * 264 + c * 8];
        }
    }
}

template <typename F4>
__device__ __forceinline__ void store_tr256(u16* smem, u16* gbase, size_t ldg,
                                            int wm, int wn, int ln, int quad,
                                            int tid, F4 val4) {
    for (int qr = 0; qr < 4; qr++) {
        __syncthreads();
        if (wn == qr) {
#pragma unroll
            for (int mt = 0; mt < 8; mt++)
#pragma unroll
                for (int nt = 0; nt < 4; nt++) {
                    ushort4 v = val4(mt, nt);
                    *(ushort4*)&smem[(nt * 16 + ln) * 264 + wm * 128 + mt * 16 + quad * 4] = v;
                }
        }
        __syncthreads();
#pragma unroll
        for (int j = 0; j < 4; j++) {
            int flat = j * 512 + tid;
            int c = flat >> 5, r8 = flat & 31;
            *(uint4*)&gbase[(size_t)(qr * 64 + c) * ldg + r8 * 8] =
                *(const uint4*)&smem[c * 264 + r8 * 8];
        }
    }
}

// ===========================================================================
// Cast f32 -> bf16.
// ===========================================================================
__global__ __launch_bounds__(256) void k_cast_bf16(
    const float* __restrict__ x, u16* __restrict__ o) {
    size_t i = ((size_t)blockIdx.x * 256 + threadIdx.x) * 4;
    float4 v = *(const float4*)&x[i];
    ushort4 p;
    p.x = f2bf(v.x); p.y = f2bf(v.y); p.z = f2bf(v.z); p.w = f2bf(v.w);
    *(ushort4*)&o[i] = p;
}

// ---------------------------------------------------------------------------
// Prep (one launch): z=0 Wq->Wqkt rows 0-255, z=1 Wk->Wqkt rows 256-511,
// z=2 Wv cast -> Wv16, z=3 Wd->Wdt, z=4 bias prep.
// ---------------------------------------------------------------------------
__global__ __launch_bounds__(256) void k_prep(
    const float* __restrict__ Wq, const float* __restrict__ Wk,
    const float* __restrict__ Wv, const float* __restrict__ Wd,
    const float* __restrict__ bv, const float* __restrict__ bd,
    const float* __restrict__ bq, const float* __restrict__ bk,
    u16* __restrict__ Wqkt, u16* __restrict__ Wv16, u16* __restrict__ Wdt,
    float* __restrict__ bc, float* __restrict__ bqk) {
    const int z = blockIdx.z;
    const int t = threadIdx.x;
    if (z == 4) {
        int id = blockIdx.y * 32 + blockIdx.x;
        if (id < 16) {
            __shared__ float red[4][64];
            int n = id * 64 + (t & 63);
            int dc = t >> 6;
            float s = 0.f;
            for (int d = dc * 256; d < dc * 256 + 256; d++)
                s += bv[d] * Wd[(size_t)d * 1024 + n];
            red[dc][t & 63] = s;
            __syncthreads();
            if (dc == 0) bc[n] = bd[n] + red[0][t & 63] + red[1][t & 63] + red[2][t & 63] + red[3][t & 63];
        } else if (id == 16) {
            for (int i = t; i < 512; i += 256) {
                float v = 0.f;
                if (i < KREAL) v = bq[i];
                else if (i >= 256 && i < 256 + KREAL) v = bk[i - 256];
                bqk[i] = v;
            }
        }
        return;
    }
    __shared__ u16 tile[32][33];
    int k0 = blockIdx.x * 32, n0 = blockIdx.y * 32;
    int tx = t & 31, ty = t >> 5;
    if (z == 2) {
        for (int i = ty; i < 32; i += 8) {
            size_t idx = (size_t)(k0 + i) * 1024 + n0 + tx;
            Wv16[idx] = f2bf(Wv[idx]);
        }
        return;
    }
    const float* W; u16* out; int N, Npad, rowoff;
    if (z == 0)      { W = Wq; out = Wqkt; N = KREAL; Npad = 256;  rowoff = 0;   }
    else if (z == 1) { W = Wk; out = Wqkt; N = KREAL; Npad = 256;  rowoff = 256; }
    else             { W = Wd; out = Wdt;  N = 1024;  Npad = 1024; rowoff = 0;   }
    if (n0 >= Npad) return;
    for (int i = ty; i < 32; i += 8) {
        int n = n0 + tx;
        tile[i][tx] = (n < N) ? f2bf(W[(size_t)(k0 + i) * N + n]) : (u16)0;
    }
    __syncthreads();
    for (int i = ty; i < 32; i += 8) {
        int n = n0 + i;
        if (n < Npad) out[(size_t)(rowoff + n) * 1024 + k0 + tx] = tile[tx][i];
    }
}

// ---------------------------------------------------------------------------
// Small GEMM (64x64 tiles): Wvdt[j][i] = sum_k Wv[i][k]*Wd[k][j].
// ---------------------------------------------------------------------------
__global__ __launch_bounds__(256) void k_gemm64(
    const u16* __restrict__ A, const u16* __restrict__ Bt,
    u16* __restrict__ C, int ldc) {
    __shared__ u16 As[64 * 64];
    __shared__ u16 Bs[64 * 64];
    const int tid = threadIdx.x;
    const int m0 = blockIdx.x * 64, n0 = blockIdx.y * 64;
    const int lane = tid & 63, w = tid >> 6;
    const int ln = lane & 15, quad = lane >> 4;

    floatx4 acc[4];
    floatx4 zero = {0.f, 0.f, 0.f, 0.f};
#pragma unroll
    for (int nt = 0; nt < 4; nt++) acc[nt] = zero;

    for (int kt = 0; kt < 16; kt++) {
        __syncthreads();
        stage64(A + (size_t)m0 * 1024 + kt * 64, 1024, As, tid);
        stage64(Bt + (size_t)n0 * 1024 + kt * 64, 1024, Bs, tid);
        __syncthreads();
#pragma unroll
        for (int kk = 0; kk < 2; kk++) {
            short8 av = frag(As, w * 16 + ln, kk * 4 + quad);
#pragma unroll
            for (int nt = 0; nt < 4; nt++) {
                short8 bvf = frag(Bs, nt * 16 + ln, kk * 4 + quad);
                acc[nt] = __builtin_amdgcn_mfma_f32_16x16x32_bf16(av, bvf, acc[nt], 0, 0, 0);
            }
        }
    }
    const int row0 = m0 + w * 16 + quad * 4;
#pragma unroll
    for (int nt = 0; nt < 4; nt++) {
        const int col = n0 + nt * 16 + ln;
        ushort4 pk;
        pk.x = f2bf(acc[nt][0]); pk.y = f2bf(acc[nt][1]);
        pk.z = f2bf(acc[nt][2]); pk.w = f2bf(acc[nt][3]);
        *reinterpret_cast<ushort4*>(&C[(size_t)col * ldc + row0]) = pk;
    }
}

// ---------------------------------------------------------------------------
// Merged projection, 256x256 8-phase core.
// XCD-chunked swizzle (chunk=48): by = l%6 -> each XCD sees all 6 B panels
// (3 MB, L2-resident) and 8 consecutive A slabs each shared by 6 blocks.
// grid (64, 6), 512 threads.
// ---------------------------------------------------------------------------
__global__ __launch_bounds__(512, 2) void k_proj2(
    const u16* __restrict__ A, const u16* __restrict__ Wqkt,
    const u16* __restrict__ Wvdt, const float* __restrict__ bqk,
    u16* __restrict__ qkp, u16* __restrict__ ut) {
    __shared__ __align__(16) u16 lds[65536];
    const int tid = threadIdx.x;
    int lin = blockIdx.x + (blockIdx.y << 6);          // [0,384)
    int l = (lin & 7) * 48 + (lin >> 3);               // bijective XCD chunk
    const int by = l % 6;
    const int m0 = (l / 6) * 256;
    const int lane = tid & 63, w = tid >> 6;
    const int wm = w >> 2, wn = w & 3;
    const int ln = lane & 15, quad = lane >> 4;

    floatx4 acc[8][4];
    floatx4 zero = {0.f, 0.f, 0.f, 0.f};
#pragma unroll
    for (int mt = 0; mt < 8; mt++)
#pragma unroll
        for (int nt = 0; nt < 4; nt++) acc[mt][nt] = zero;

    const u16* Ag = A + (size_t)m0 * 1024;
    const int n0 = (by < 2) ? by * 256 : (by - 2) * 256;
    const u16* Bg = (by < 2) ? (Wqkt + (size_t)n0 * 1024) : (Wvdt + (size_t)n0 * 1024);
    gemm_core256<16>(Ag, 1024, Bg, 1024, lds, tid, acc);

    if (by < 2) {
        float b4[4];
#pragma unroll
        for (int nt = 0; nt < 4; nt++) b4[nt] = bqk[n0 + wn * 64 + nt * 16 + ln];
        store_rm256(lds, qkp + (size_t)m0 * 512 + n0, 512, wm, wn, ln, quad, tid,
            [&](int mt, int nt, int r) -> u16 {
                return f2bf(acc[mt][nt][r] + b4[nt]);
            });
    } else {
        int b = m0 >> 11, s0loc = m0 & 2047;
        store_tr256(lds, ut + ((size_t)b * DD + n0) * SS + s0loc, SS, wm, wn, ln, quad, tid,
            [&](int mt, int nt) -> ushort4 {
                ushort4 pk;
                pk.x = f2bf(acc[mt][nt][0]); pk.y = f2bf(acc[mt][nt][1]);
                pk.z = f2bf(acc[mt][nt][2]); pk.w = f2bf(acc[mt][nt][3]);
                return pk;
            });
    }
}

// ---------------------------------------------------------------------------
// QK GEMM (all 8 batches): P = bf16(exp(q.k - 30)); row sums via atomics.
// XCD-chunked swizzle (chunk=64): one batch per XCD -> qkp batch (2 MB)
// L2-resident. grid (8, 8, 8), 512 threads.
// ---------------------------------------------------------------------------
__global__ __launch_bounds__(512, 2) void k_qk2(
    const u16* __restrict__ qkp, u16* __restrict__ P, float* __restrict__ lg) {
    __shared__ __align__(16) u16 lds[65536];
    const int tid = threadIdx.x;
    int lin = blockIdx.x + (blockIdx.y << 3) + (blockIdx.z << 6);  // [0,512)
    int l = ((lin & 7) << 6) + (lin >> 3);
    const int bb = l >> 6, rem = l & 63;
    const int s0 = (rem & 7) * 256, t0 = (rem >> 3) * 256;
    const int lane = tid & 63, w = tid >> 6;
    const int wm = w >> 2, wn = w & 3;
    const int ln = lane & 15, quad = lane >> 4;

    floatx4 acc[8][4];
    floatx4 zero = {0.f, 0.f, 0.f, 0.f};
#pragma unroll
    for (int mt = 0; mt < 8; mt++)
#pragma unroll
        for (int nt = 0; nt < 4; nt++) acc[mt][nt] = zero;

    gemm_core256<4>(qkp + ((size_t)bb * SS + s0) * 512, 512,
                    qkp + ((size_t)bb * SS + t0) * 512 + 256, 512, lds, tid, acc);

    // exp in place, then row-sums
#pragma unroll
    for (int mt = 0; mt < 8; mt++)
#pragma unroll
        for (int nt = 0; nt < 4; nt++)
#pragma unroll
            for (int r = 0; r < 4; r++)
                acc[mt][nt][r] = __expf(acc[mt][nt][r] - 30.f);

#pragma unroll
    for (int mt = 0; mt < 8; mt++) {
#pragma unroll
        for (int r = 0; r < 4; r++) {
            float rs = acc[mt][0][r] + acc[mt][1][r] + acc[mt][2][r] + acc[mt][3][r];
            rs += __shfl_xor(rs, 1);
            rs += __shfl_xor(rs, 2);
            rs += __shfl_xor(rs, 4);
            rs += __shfl_xor(rs, 8);
            if (ln == 0)
                atomicAdd(&lg[(size_t)bb * SS + s0 + wm * 128 + mt * 16 + quad * 4 + r], rs);
        }
    }

    store_rm256(lds, P + (size_t)bb * SS * SS + (size_t)s0 * SS + t0, SS,
                wm, wn, ln, quad, tid,
        [&](int mt, int nt, int r) -> u16 { return f2bf(acc[mt][nt][r]); });
}

// ---------------------------------------------------------------------------
// Final GEMM (all 8 batches, one launch): out = (P.ut)/l + bc + x  (f32,
// straight into d_out; LN runs in-place afterwards).
// XCD-chunked swizzle (chunk=32): exactly one batch per XCD (32 blocks on
// 32 CUs; ut batch 4.2 MB ~L2-resident, P slabs shared by 4 d-blocks on the
// same L2). Epilogue: raw acc bounced through LDS; /l + bc + xres applied in
// the copy-out phase with fully-coalesced float4 loads by all 512 threads.
// grid (8, 4, 8), 512 threads.
// ---------------------------------------------------------------------------
__global__ __launch_bounds__(512, 2) void k_h2(
    const u16* __restrict__ P, const u16* __restrict__ ut,
    const float* __restrict__ lg, const float* __restrict__ bc,
    const float* __restrict__ xres, float* __restrict__ out) {
    __shared__ __align__(16) u16 lds[65536];
    const int tid = threadIdx.x;
    int lin = blockIdx.x + (blockIdx.y << 3) + (blockIdx.z << 5);  // [0,256)
    int l = ((lin & 7) << 5) + (lin >> 3);
    const int bb = l >> 5, rem = l & 31;
    const int s0 = (rem & 7) * 256, d0 = (rem >> 3) * 256;
    const int lane = tid & 63, w = tid >> 6;
    const int wm = w >> 2, wn = w & 3;
    const int ln = lane & 15, quad = lane >> 4;

    floatx4 acc[8][4];
    floatx4 zero = {0.f, 0.f, 0.f, 0.f};
#pragma unroll
    for (int mt = 0; mt < 8; mt++)
#pragma unroll
        for (int nt = 0; nt < 4; nt++) acc[mt][nt] = zero;

    gemm_core256<32>(P + ((size_t)bb * SS + s0) * SS, SS,
                     ut + ((size_t)bb * DD + d0) * SS, SS, lds, tid, acc);

    float* smem = (float*)lds;
    float* outb = out + ((size_t)bb * SS + s0) * DD + d0;
    const float* xb = xres + ((size_t)bb * SS + s0) * DD + d0;
    for (int c4 = 0; c4 < 4; c4++) {
        __syncthreads();
        if (wm == (c4 >> 1)) {
#pragma unroll
            for (int i = 0; i < 4; i++)
#pragma unroll
                for (int nt = 0; nt < 4; nt++)
#pragma unroll
                    for (int r = 0; r < 4; r++)
                        smem[(i * 16 + quad * 4 + r) * 260 + wn * 64 + nt * 16 + ln] =
                            acc[(c4 & 1) * 4 + i][nt][r];
        }
        __syncthreads();
#pragma unroll
        for (int j = 0; j < 8; j++) {
            int flat = j * 512 + tid;
            int row = flat >> 6, q = flat & 63;
            size_t grow = (size_t)bb * SS + s0 + c4 * 64 + row;
            float iv = 1.f / lg[grow];
            float4 a  = *(const float4*)&smem[row * 260 + q * 4];
            float4 b4 = *(const float4*)&bc[d0 + q * 4];
            float4 xr = *(const float4*)&xb[(size_t)(c4 * 64 + row) * DD + q * 4];
            float4 o;
            o.x = a.x * iv + b4.x + xr.x;
            o.y = a.y * iv + b4.y + xr.y;
            o.z = a.z * iv + b4.z + xr.z;
            o.w = a.w * iv + b4.w + xr.w;
            *(float4*)&outb[(size_t)(c4 * 64 + row) * DD + q * 4] = o;
        }
    }
}

// ---------------------------------------------------------------------------
// LayerNorm over last dim (1024), f32 IN-PLACE on d_out. Each block owns 4
// rows exclusively -> no cross-block hazard.
// ---------------------------------------------------------------------------
__global__ __launch_bounds__(256) void k_ln_f32(
    float* __restrict__ io, const float* __restrict__ gamma,
    const float* __restrict__ beta) {
    const int tid = threadIdx.x;
    const int lane = tid & 63, w = tid >> 6;
    const size_t row = (size_t)blockIdx.x * 4 + w;
    float* rp = io + row * DD;

    float v[16];
#pragma unroll
    for (int j = 0; j < 4; j++) {
        float4 t = *(const float4*)&rp[j * 256 + lane * 4];
        v[j * 4 + 0] = t.x; v[j * 4 + 1] = t.y; v[j * 4 + 2] = t.z; v[j * 4 + 3] = t.w;
    }
    float s = 0.f, sq = 0.f;
#pragma unroll
    for (int i = 0; i < 16; i++) { s += v[i]; sq += v[i] * v[i]; }
#pragma unroll
    for (int msk = 1; msk < 64; msk <<= 1) {
        s  += __shfl_xor(s,  msk, 64);
        sq += __shfl_xor(sq, msk, 64);
    }
    float mean = s * (1.f / 1024.f);
    float var  = sq * (1.f / 1024.f) - mean * mean;
    float rstd = rsqrtf(fmaxf(var, 0.f) + 1e-12f);
#pragma unroll
    for (int j = 0; j < 4; j++) {
        float4 g  = *(const float4*)&gamma[j * 256 + lane * 4];
        float4 bt = *(const float4*)&beta [j * 256 + lane * 4];
        float4 o;
        o.x = g.x * (v[j * 4 + 0] - mean) * rstd + bt.x;
        o.y = g.y * (v[j * 4 + 1] - mean) * rstd + bt.y;
        o.z = g.z * (v[j * 4 + 2] - mean) * rstd + bt.z;
        o.w = g.w * (v[j * 4 + 3] - mean) * rstd + bt.w;
        *(float4*)&rp[j * 256 + lane * 4] = o;
    }
}

// ---------------------------------------------------------------------------
extern "C" void kernel_launch(void* const* d_in, const int* in_sizes, int n_in,
                              void* d_out, int out_size, void* d_ws, size_t ws_size,
                              hipStream_t stream) {
    const float* x     = (const float*)d_in[0];
    const float* Wq    = (const float*)d_in[2];
    const float* bq    = (const float*)d_in[3];
    const float* Wk    = (const float*)d_in[4];
    const float* bk    = (const float*)d_in[5];
    const float* Wv    = (const float*)d_in[6];
    const float* bv    = (const float*)d_in[7];
    const float* Wd    = (const float*)d_in[8];
    const float* bd    = (const float*)d_in[9];
    const float* gamma = (const float*)d_in[10];
    const float* beta  = (const float*)d_in[11];
    float* out = (float*)d_out;

    // Workspace (~112.1 MB used, 122.7 proven usable):
    //   [0, 16.78M)        qkp  [16384][512] bf16
    //   [16.78M, 50.33M)   ut   [8][1024][2048] bf16
    //   [50.33M, 117.44M)  P    [8][2048][2048] bf16
    //       aliases (dead before qk writes P):
    //         x16  @ 50.33M (33.55M), Wv16 @ 83.89M, Wvdt @ 85.98M,
    //         Wdt @ 88.08M, Wqkt @ 90.18M
    //   [117.44M, ..)      lg (64K), bc (4K), bqk (2K)
    char* ws = (char*)d_ws;
    u16*   qkp  = (u16*)(ws + 0);
    u16*   ut   = (u16*)(ws + 16777216);
    u16*   P    = (u16*)(ws + 50331648);
    u16*   x16  = (u16*)(ws + 50331648);
    u16*   Wv16 = (u16*)(ws + 83886080);
    u16*   Wvdt = (u16*)(ws + 85983232);
    u16*   Wdt  = (u16*)(ws + 88080384);
    u16*   Wqkt = (u16*)(ws + 90177536);
    float* lg   = (float*)(ws + 117440512);
    float* bc   = (float*)(ws + 117506048);
    float* bqk  = (float*)(ws + 117510144);

    k_cast_bf16<<<dim3(16384), dim3(256), 0, stream>>>(x, x16);
    k_prep<<<dim3(32, 32, 5), dim3(256), 0, stream>>>(Wq, Wk, Wv, Wd, bv, bd, bq, bk,
                                                      Wqkt, Wv16, Wdt, bc, bqk);
    k_gemm64<<<dim3(16, 16), dim3(256), 0, stream>>>(Wv16, Wdt, Wvdt, 1024);

    k_proj2<<<dim3(64, 6), dim3(512), 0, stream>>>(x16, Wqkt, Wvdt, bqk, qkp, ut);

    hipMemsetAsync(lg, 0, (size_t)BB * SS * sizeof(float), stream);

    k_qk2<<<dim3(8, 8, 8), dim3(512), 0, stream>>>(qkp, P, lg);
    k_h2 <<<dim3(8, 4, 8), dim3(512), 0, stream>>>(P, ut, lg, bc, x, out);

    k_ln_f32<<<dim3(4096), dim3(256), 0, stream>>>(out, gamma, beta);
}

// Round 3
// 372.534 us; speedup vs baseline: 1.1503x; 1.1503x over previous
//
#include <hip/hip_runtime.h>
#include <stdint.h>

#define BB 8
#define SS 2048
#define DD 1024
#define KREAL 204

typedef __attribute__((ext_vector_type(8))) short short8;
typedef __attribute__((ext_vector_type(4))) float floatx4;
typedef uint16_t u16;
typedef uint32_t u32;

__device__ __forceinline__ float bf2f(u16 u) {
    union { float f; u32 i; } c; c.i = ((u32)u) << 16; return c.f;
}
__device__ __forceinline__ u16 f2bf(float f) {
    union { float f; u32 i; } c; c.f = f;
    u32 i = c.i;
    u32 r = (i + 0x7FFFu + ((i >> 16) & 1u)) >> 16;
    return (u16)r;
}

#if defined(__has_builtin)
#if __has_builtin(__builtin_amdgcn_global_load_lds)
#define HAVE_GLL 1
#endif
#endif

__device__ __forceinline__ void gload16(const u16* g, u16* l) {
#ifdef HAVE_GLL
    __builtin_amdgcn_global_load_lds(
        (const __attribute__((address_space(1))) void*)(uintptr_t)g,
        (__attribute__((address_space(3))) void*)(u32)(uintptr_t)(void*)l,
        16, 0, 0);
#else
    *(uint4*)l = *(const uint4*)g;
#endif
}

#define VM_WAIT(N) asm volatile("s_waitcnt vmcnt(" #N ")" ::: "memory")
#define S_BAR()    asm volatile("s_barrier" ::: "memory")

// ===========================================================================
// Legacy 64-wide-row swizzled staging (kept for k_gemm64 only).
// ===========================================================================
__device__ __forceinline__ void stage64(const u16* __restrict__ src, size_t ld,
                                        u16* lds, int tid) {
#pragma unroll
    for (int j = 0; j < 2; j++) {
        int flat = j * 256 + tid;
        int row = flat >> 3, slot = flat & 7;
        int kg = slot ^ (row & 7);
        gload16(src + (size_t)row * ld + kg * 8, lds + flat * 8);
    }
}
__device__ __forceinline__ short8 frag(const u16* lds, int row, int kslot) {
    return *(const short8*)&lds[(row << 6) + (((kslot ^ (row & 7)) & 7) << 3)];
}

// ===========================================================================
// Parametrized 8-wave GEMM core, BM=256, BN in {256,128}, BK=64 as two
// K-half planes of 32. Staging via global_load_lds with pre-swizzled SOURCE
// (kg = slot ^ ((row>>1)&3)); frag reads apply the matching XOR -> max 2-way
// bank aliasing (free; SQ_LDS_BANK_CONFLICT == 0 verified rounds 1-2).
// Counted-vmcnt protocol, never drains to 0 in the main loop:
//   NB=256: 8 loads/tile, VM(8)/VM(8), tail VM(4)/VM(0), prologue 12.
//   NB=128: 6 loads/tile, VM(6)/VM(6), tail VM(3)/VM(0), prologue 9.
// Slot-reuse safety: every stage targets a plane whose previous occupant's
// last reader completed before the barrier just crossed (per-slot verified).
// ===========================================================================
__device__ __forceinline__ short8 frag32(const u16* plane, int row, int ks) {
    return *(const short8*)&plane[(row << 5) + (((ks ^ ((row >> 1) & 3)) & 3) << 3)];
}

template <int MT0, int MTN, int MTOT, bool LOADB>
__device__ __forceinline__ void phaseN(const u16* Apl, const u16* Bpl,
                                       int arow, int brow, int ln, int quad,
                                       short8 (&bv)[4], floatx4 (&acc)[MTOT][4]) {
    short8 af[MTN];
#pragma unroll
    for (int i = 0; i < MTN; i++) af[i] = frag32(Apl, arow + (MT0 + i) * 16 + ln, quad);
    if (LOADB) {
#pragma unroll
        for (int nt = 0; nt < 4; nt++) bv[nt] = frag32(Bpl, brow + nt * 16 + ln, quad);
    }
    __builtin_amdgcn_s_setprio(1);
#pragma unroll
    for (int i = 0; i < MTN; i++)
#pragma unroll
        for (int nt = 0; nt < 4; nt++)
            acc[MT0 + i][nt] = __builtin_amdgcn_mfma_f32_16x16x32_bf16(
                af[i], bv[nt], acc[MT0 + i][nt], 0, 0, 0);
    __builtin_amdgcn_s_setprio(0);
}

template <int NT, int NB, int MTOT>
__device__ __forceinline__ void gemm_core(
    const u16* __restrict__ Ag, size_t lda,
    const u16* __restrict__ Bg, size_t ldb,
    u16* lds, int tid, floatx4 (&acc)[MTOT][4]) {
    constexpr int BPL = NB * 32;   // B plane size in u16
    constexpr int MH = MTOT / 2;
    const int lane = tid & 63, w = tid >> 6;
    const int arow = (NB == 256) ? (w >> 2) * 128 : (w >> 1) * 64;
    const int brow = (NB == 256) ? (w & 3) * 64  : (w & 1) * 64;
    const int ln = lane & 15, quad = lane >> 4;
    const int srow = tid >> 2;
    const int kgp = (tid & 3) ^ ((srow >> 1) & 3);
    const u16* A0 = Ag + (size_t)srow * lda + kgp * 8;
    const u16* A1 = Ag + (size_t)(srow + 128) * lda + kgp * 8;
    const u16* B0 = Bg + (size_t)srow * ldb + kgp * 8;
    const u16* B1 = Bg + (size_t)(srow + 128) * ldb + kgp * 8;
    u16* Al = lds;
    u16* Bl = lds + 4 * 8192;

    auto stageA = [&](size_t koff, int plane) {
        gload16(A0 + koff, Al + plane * 8192 + tid * 8);
        gload16(A1 + koff, Al + plane * 8192 + 4096 + tid * 8);
    };
    auto stageB = [&](size_t koff, int plane) {
        gload16(B0 + koff, Bl + plane * BPL + tid * 8);
        if constexpr (NB == 256)
            gload16(B1 + koff, Bl + plane * BPL + 4096 + tid * 8);
    };

    // prologue: (0,Ak0)(0,Bk0)(0,Ak1)(0,Bk1)(1,Ak0)(1,Bk0)
    stageA(0, 0);  stageB(0, 0);
    stageA(32, 1); stageB(32, 1);
    stageA(64, 2); stageB(64, 2);

    short8 bv[4];
#pragma unroll 2
    for (int t = 0; t < NT - 1; ++t) {
        const int p = (t & 1) * 2, pn = 2 - p;
        const u16* Ap0 = Al + p * 8192;  const u16* Ap1 = Ap0 + 8192;
        const u16* Bp0 = Bl + p * BPL;   const u16* Bp1 = Bp0 + BPL;
        const size_t o1 = (size_t)(t + 1) * 64;
        const size_t o2 = (size_t)(t + 2) * 64;
        if constexpr (NB == 256) { VM_WAIT(8); } else { VM_WAIT(6); }
        S_BAR();
        stageA(o1 + 32, pn + 1);
        phaseN<0, MH, MTOT, true >(Ap0, Bp0, arow, brow, ln, quad, bv, acc);
        stageB(o1 + 32, pn + 1);
        phaseN<MH, MH, MTOT, false>(Ap0, Bp0, arow, brow, ln, quad, bv, acc);
        if constexpr (NB == 256) { VM_WAIT(8); } else { VM_WAIT(6); }
        S_BAR();
        if (t + 2 < NT) stageA(o2, p);
        phaseN<0, MH, MTOT, true >(Ap1, Bp1, arow, brow, ln, quad, bv, acc);
        if (t + 2 < NT) stageB(o2, p);
        phaseN<MH, MH, MTOT, false>(Ap1, Bp1, arow, brow, ln, quad, bv, acc);
    }
    {   // peel t = NT-1
        const int p = ((NT - 1) & 1) * 2;
        const u16* Ap0 = Al + p * 8192;  const u16* Ap1 = Ap0 + 8192;
        const u16* Bp0 = Bl + p * BPL;   const u16* Bp1 = Bp0 + BPL;
        if constexpr (NB == 256) { VM_WAIT(4); } else { VM_WAIT(3); }
        S_BAR();
        phaseN<0, MH, MTOT, true >(Ap0, Bp0, arow, brow, ln, quad, bv, acc);
        phaseN<MH, MH, MTOT, false>(Ap0, Bp0, arow, brow, ln, quad, bv, acc);
        VM_WAIT(0); S_BAR();
        phaseN<0, MH, MTOT, true >(Ap1, Bp1, arow, brow, ln, quad, bv, acc);
        phaseN<MH, MH, MTOT, false>(Ap1, Bp1, arow, brow, ln, quad, bv, acc);
    }
}

// ===========================================================================
// Epilogue stores for the 256x256 tile (LDS bounce -> contiguous dwordx4).
// ===========================================================================
template <typename F>
__device__ __forceinline__ void store_rm256(u16* smem, u16* gbase, size_t ldc,
                                            int wm, int wn, int ln, int quad,
                                            int tid, F val) {
    for (int half = 0; half < 2; half++) {
        __syncthreads();
        if (wm == half) {
#pragma unroll
            for (int mt = 0; mt < 8; mt++)
#pragma unroll
                for (int nt = 0; nt < 4; nt++)
#pragma unroll
                    for (int r = 0; r < 4; r++)
                        smem[(mt * 16 + quad * 4 + r) * 264 + wn * 64 + nt * 16 + ln] =
                            val(mt, nt, r);
        }
        __syncthreads();
#pragma unroll
        for (int j = 0; j < 8; j++) {
            int flat = j * 512 + tid;
            int row = flat >> 5, c = flat & 31;
            *(uint4*)&gbase[(size_t)(half * 128 + row) * ldc + c * 8] =
                *(const uint4*)&smem[row * 264 + c * 8];
        }
    }
}

template <typename F4>
__device__ __forceinline__ void store_tr256(u16* smem, u16* gbase, size_t ldg,
                                            int wm, int wn, int ln, int quad,
                                            int tid, F4 val4) {
    for (int qr = 0; qr < 4; qr++) {
        __syncthreads();
        if (wn == qr) {
#pragma unroll
            for (int mt = 0; mt < 8; mt++)
#pragma unroll
                for (int nt = 0; nt < 4; nt++) {
                    ushort4 v = val4(mt, nt);
                    *(ushort4*)&smem[(nt * 16 + ln) * 264 + wm * 128 + mt * 16 + quad * 4] = v;
                }
        }
        __syncthreads();
#pragma unroll
        for (int j = 0; j < 4; j++) {
            int flat = j * 512 + tid;
            int c = flat >> 5, r8 = flat & 31;
            *(uint4*)&gbase[(size_t)(qr * 64 + c) * ldg + r8 * 8] =
                *(const uint4*)&smem[c * 264 + r8 * 8];
        }
    }
}

// ===========================================================================
// Cast f32 -> bf16.
// ===========================================================================
__global__ __launch_bounds__(256) void k_cast_bf16(
    const float* __restrict__ x, u16* __restrict__ o) {
    size_t i = ((size_t)blockIdx.x * 256 + threadIdx.x) * 4;
    float4 v = *(const float4*)&x[i];
    ushort4 p;
    p.x = f2bf(v.x); p.y = f2bf(v.y); p.z = f2bf(v.z); p.w = f2bf(v.w);
    *(ushort4*)&o[i] = p;
}

// ---------------------------------------------------------------------------
// Prep (one launch): z=0 Wq->Wqkt rows 0-255, z=1 Wk->Wqkt rows 256-511,
// z=2 Wv cast -> Wv16, z=3 Wd->Wdt, z=4 bias prep.
// ---------------------------------------------------------------------------
__global__ __launch_bounds__(256) void k_prep(
    const float* __restrict__ Wq, const float* __restrict__ Wk,
    const float* __restrict__ Wv, const float* __restrict__ Wd,
    const float* __restrict__ bv, const float* __restrict__ bd,
    const float* __restrict__ bq, const float* __restrict__ bk,
    u16* __restrict__ Wqkt, u16* __restrict__ Wv16, u16* __restrict__ Wdt,
    float* __restrict__ bc, float* __restrict__ bqk) {
    const int z = blockIdx.z;
    const int t = threadIdx.x;
    if (z == 4) {
        int id = blockIdx.y * 32 + blockIdx.x;
        if (id < 16) {
            __shared__ float red[4][64];
            int n = id * 64 + (t & 63);
            int dc = t >> 6;
            float s = 0.f;
            for (int d = dc * 256; d < dc * 256 + 256; d++)
                s += bv[d] * Wd[(size_t)d * 1024 + n];
            red[dc][t & 63] = s;
            __syncthreads();
            if (dc == 0) bc[n] = bd[n] + red[0][t & 63] + red[1][t & 63] + red[2][t & 63] + red[3][t & 63];
        } else if (id == 16) {
            for (int i = t; i < 512; i += 256) {
                float v = 0.f;
                if (i < KREAL) v = bq[i];
                else if (i >= 256 && i < 256 + KREAL) v = bk[i - 256];
                bqk[i] = v;
            }
        }
        return;
    }
    __shared__ u16 tile[32][33];
    int k0 = blockIdx.x * 32, n0 = blockIdx.y * 32;
    int tx = t & 31, ty = t >> 5;
    if (z == 2) {
        for (int i = ty; i < 32; i += 8) {
            size_t idx = (size_t)(k0 + i) * 1024 + n0 + tx;
            Wv16[idx] = f2bf(Wv[idx]);
        }
        return;
    }
    const float* W; u16* out; int N, Npad, rowoff;
    if (z == 0)      { W = Wq; out = Wqkt; N = KREAL; Npad = 256;  rowoff = 0;   }
    else if (z == 1) { W = Wk; out = Wqkt; N = KREAL; Npad = 256;  rowoff = 256; }
    else             { W = Wd; out = Wdt;  N = 1024;  Npad = 1024; rowoff = 0;   }
    if (n0 >= Npad) return;
    for (int i = ty; i < 32; i += 8) {
        int n = n0 + tx;
        tile[i][tx] = (n < N) ? f2bf(W[(size_t)(k0 + i) * N + n]) : (u16)0;
    }
    __syncthreads();
    for (int i = ty; i < 32; i += 8) {
        int n = n0 + i;
        if (n < Npad) out[(size_t)(rowoff + n) * 1024 + k0 + tx] = tile[tx][i];
    }
}

// ---------------------------------------------------------------------------
// Small GEMM (64x64 tiles): Wvdt[j][i] = sum_k Wv[i][k]*Wd[k][j].
// ---------------------------------------------------------------------------
__global__ __launch_bounds__(256) void k_gemm64(
    const u16* __restrict__ A, const u16* __restrict__ Bt,
    u16* __restrict__ C, int ldc) {
    __shared__ u16 As[64 * 64];
    __shared__ u16 Bs[64 * 64];
    const int tid = threadIdx.x;
    const int m0 = blockIdx.x * 64, n0 = blockIdx.y * 64;
    const int lane = tid & 63, w = tid >> 6;
    const int ln = lane & 15, quad = lane >> 4;

    floatx4 acc[4];
    floatx4 zero = {0.f, 0.f, 0.f, 0.f};
#pragma unroll
    for (int nt = 0; nt < 4; nt++) acc[nt] = zero;

    for (int kt = 0; kt < 16; kt++) {
        __syncthreads();
        stage64(A + (size_t)m0 * 1024 + kt * 64, 1024, As, tid);
        stage64(Bt + (size_t)n0 * 1024 + kt * 64, 1024, Bs, tid);
        __syncthreads();
#pragma unroll
        for (int kk = 0; kk < 2; kk++) {
            short8 av = frag(As, w * 16 + ln, kk * 4 + quad);
#pragma unroll
            for (int nt = 0; nt < 4; nt++) {
                short8 bvf = frag(Bs, nt * 16 + ln, kk * 4 + quad);
                acc[nt] = __builtin_amdgcn_mfma_f32_16x16x32_bf16(av, bvf, acc[nt], 0, 0, 0);
            }
        }
    }
    const int row0 = m0 + w * 16 + quad * 4;
#pragma unroll
    for (int nt = 0; nt < 4; nt++) {
        const int col = n0 + nt * 16 + ln;
        ushort4 pk;
        pk.x = f2bf(acc[nt][0]); pk.y = f2bf(acc[nt][1]);
        pk.z = f2bf(acc[nt][2]); pk.w = f2bf(acc[nt][3]);
        *reinterpret_cast<ushort4*>(&C[(size_t)col * ldc + row0]) = pk;
    }
}

// ---------------------------------------------------------------------------
// Merged projection, 256x256 core, identity block mapping (swizzle reverted:
// round-2 showed XCD chunking serializes L2 misses here; L3-fit regime).
// grid (64, 6), 512 threads.
// ---------------------------------------------------------------------------
__global__ __launch_bounds__(512, 2) void k_proj2(
    const u16* __restrict__ A, const u16* __restrict__ Wqkt,
    const u16* __restrict__ Wvdt, const float* __restrict__ bqk,
    u16* __restrict__ qkp, u16* __restrict__ ut) {
    __shared__ __align__(16) u16 lds[65536];
    const int tid = threadIdx.x;
    const int m0 = blockIdx.x * 256;
    const int by = blockIdx.y;
    const int lane = tid & 63, w = tid >> 6;
    const int wm = w >> 2, wn = w & 3;
    const int ln = lane & 15, quad = lane >> 4;

    floatx4 acc[8][4];
    floatx4 zero = {0.f, 0.f, 0.f, 0.f};
#pragma unroll
    for (int mt = 0; mt < 8; mt++)
#pragma unroll
        for (int nt = 0; nt < 4; nt++) acc[mt][nt] = zero;

    const u16* Ag = A + (size_t)m0 * 1024;
    const int n0 = (by < 2) ? by * 256 : (by - 2) * 256;
    const u16* Bg = (by < 2) ? (Wqkt + (size_t)n0 * 1024) : (Wvdt + (size_t)n0 * 1024);
    gemm_core<16, 256, 8>(Ag, 1024, Bg, 1024, lds, tid, acc);

    if (by < 2) {
        float b4[4];
#pragma unroll
        for (int nt = 0; nt < 4; nt++) b4[nt] = bqk[n0 + wn * 64 + nt * 16 + ln];
        store_rm256(lds, qkp + (size_t)m0 * 512 + n0, 512, wm, wn, ln, quad, tid,
            [&](int mt, int nt, int r) -> u16 {
                return f2bf(acc[mt][nt][r] + b4[nt]);
            });
    } else {
        int b = m0 >> 11, s0loc = m0 & 2047;
        store_tr256(lds, ut + ((size_t)b * DD + n0) * SS + s0loc, SS, wm, wn, ln, quad, tid,
            [&](int mt, int nt) -> ushort4 {
                ushort4 pk;
                pk.x = f2bf(acc[mt][nt][0]); pk.y = f2bf(acc[mt][nt][1]);
                pk.z = f2bf(acc[mt][nt][2]); pk.w = f2bf(acc[mt][nt][3]);
                return pk;
            });
    }
}

// ---------------------------------------------------------------------------
// QK GEMM, 4-batch group: P = bf16(exp(q.k - 30)); row sums via atomics.
// P buffer is group-local (33.5 MB) so k_h3 reads it L3/L2-hot.
// grid (8, 8, 4), 512 threads. Identity mapping.
// ---------------------------------------------------------------------------
__global__ __launch_bounds__(512, 2) void k_qk2(
    const u16* __restrict__ qkp, u16* __restrict__ P, float* __restrict__ lg) {
    __shared__ __align__(16) u16 lds[65536];
    const int tid = threadIdx.x;
    const int s0 = blockIdx.x * 256, t0 = blockIdx.y * 256, bb = blockIdx.z;
    const int lane = tid & 63, w = tid >> 6;
    const int wm = w >> 2, wn = w & 3;
    const int ln = lane & 15, quad = lane >> 4;

    floatx4 acc[8][4];
    floatx4 zero = {0.f, 0.f, 0.f, 0.f};
#pragma unroll
    for (int mt = 0; mt < 8; mt++)
#pragma unroll
        for (int nt = 0; nt < 4; nt++) acc[mt][nt] = zero;

    gemm_core<4, 256, 8>(qkp + ((size_t)bb * SS + s0) * 512, 512,
                         qkp + ((size_t)bb * SS + t0) * 512 + 256, 512, lds, tid, acc);

#pragma unroll
    for (int mt = 0; mt < 8; mt++)
#pragma unroll
        for (int nt = 0; nt < 4; nt++)
#pragma unroll
            for (int r = 0; r < 4; r++)
                acc[mt][nt][r] = __expf(acc[mt][nt][r] - 30.f);

#pragma unroll
    for (int mt = 0; mt < 8; mt++) {
#pragma unroll
        for (int r = 0; r < 4; r++) {
            float rs = acc[mt][0][r] + acc[mt][1][r] + acc[mt][2][r] + acc[mt][3][r];
            rs += __shfl_xor(rs, 1);
            rs += __shfl_xor(rs, 2);
            rs += __shfl_xor(rs, 4);
            rs += __shfl_xor(rs, 8);
            if (ln == 0)
                atomicAdd(&lg[(size_t)bb * SS + s0 + wm * 128 + mt * 16 + quad * 4 + r], rs);
        }
    }

    store_rm256(lds, P + (size_t)bb * SS * SS + (size_t)s0 * SS + t0, SS,
                wm, wn, ln, quad, tid,
        [&](int mt, int nt, int r) -> u16 { return f2bf(acc[mt][nt][r]); });
}

// ---------------------------------------------------------------------------
// Final GEMM, 4-batch group, BM=256 x BN=128 (full-GPU grid 8x8x4=256 blocks,
// 96 KiB LDS): out = (P.ut)/l + bc + x (f32 straight into d_out; LN in-place
// after). P group (33.5 MB) is L3-hot from the immediately-preceding k_qk2.
// ---------------------------------------------------------------------------
__global__ __launch_bounds__(512, 2) void k_h3(
    const u16* __restrict__ P, const u16* __restrict__ ut,
    const float* __restrict__ lg, const float* __restrict__ bc,
    const float* __restrict__ xres, float* __restrict__ out) {
    __shared__ __align__(16) u16 lds[49152];
    const int tid = threadIdx.x;
    const int s0 = blockIdx.x * 256, d0 = blockIdx.y * 128, bb = blockIdx.z;
    const int lane = tid & 63, w = tid >> 6;
    const int ln = lane & 15, quad = lane >> 4;

    floatx4 acc[4][4];
    floatx4 zero = {0.f, 0.f, 0.f, 0.f};
#pragma unroll
    for (int mt = 0; mt < 4; mt++)
#pragma unroll
        for (int nt = 0; nt < 4; nt++) acc[mt][nt] = zero;

    gemm_core<32, 128, 4>(P + ((size_t)bb * SS + s0) * SS, SS,
                          ut + ((size_t)bb * DD + d0) * SS, SS, lds, tid, acc);

    // epilogue: bounce acc through LDS; /l + bc + xres fused into the
    // copy-out with fully-coalesced float4 traffic by all 512 threads.
    float* smem = (float*)lds;
    float* outb = out + ((size_t)bb * SS + s0) * DD + d0;
    const float* xb = xres + ((size_t)bb * SS + s0) * DD + d0;
    const float* lgb = lg + (size_t)bb * SS + s0;
    for (int c4 = 0; c4 < 4; c4++) {
        __syncthreads();
        if ((w >> 1) == c4) {
#pragma unroll
            for (int mt = 0; mt < 4; mt++)
#pragma unroll
                for (int nt = 0; nt < 4; nt++)
#pragma unroll
                    for (int r = 0; r < 4; r++)
                        smem[(mt * 16 + quad * 4 + r) * 132 + (w & 1) * 64 + nt * 16 + ln] =
                            acc[mt][nt][r];
        }
        __syncthreads();
#pragma unroll
        for (int j = 0; j < 4; j++) {
            int flat = j * 512 + tid;
            int row = flat >> 5, q = flat & 31;
            float iv = 1.f / lgb[c4 * 64 + row];
            float4 a  = *(const float4*)&smem[row * 132 + q * 4];
            float4 b4 = *(const float4*)&bc[d0 + q * 4];
            float4 xr = *(const float4*)&xb[(size_t)(c4 * 64 + row) * DD + q * 4];
            float4 o;
            o.x = a.x * iv + b4.x + xr.x;
            o.y = a.y * iv + b4.y + xr.y;
            o.z = a.z * iv + b4.z + xr.z;
            o.w = a.w * iv + b4.w + xr.w;
            *(float4*)&outb[(size_t)(c4 * 64 + row) * DD + q * 4] = o;
        }
    }
}

// ---------------------------------------------------------------------------
// LayerNorm over last dim (1024), f32 IN-PLACE on d_out. Each block owns 4
// rows exclusively -> no cross-block hazard.
// ---------------------------------------------------------------------------
__global__ __launch_bounds__(256) void k_ln_f32(
    float* __restrict__ io, const float* __restrict__ gamma,
    const float* __restrict__ beta) {
    const int tid = threadIdx.x;
    const int lane = tid & 63, w = tid >> 6;
    const size_t row = (size_t)blockIdx.x * 4 + w;
    float* rp = io + row * DD;

    float v[16];
#pragma unroll
    for (int j = 0; j < 4; j++) {
        float4 t = *(const float4*)&rp[j * 256 + lane * 4];
        v[j * 4 + 0] = t.x; v[j * 4 + 1] = t.y; v[j * 4 + 2] = t.z; v[j * 4 + 3] = t.w;
    }
    float s = 0.f, sq = 0.f;
#pragma unroll
    for (int i = 0; i < 16; i++) { s += v[i]; sq += v[i] * v[i]; }
#pragma unroll
    for (int msk = 1; msk < 64; msk <<= 1) {
        s  += __shfl_xor(s,  msk, 64);
        sq += __shfl_xor(sq, msk, 64);
    }
    float mean = s * (1.f / 1024.f);
    float var  = sq * (1.f / 1024.f) - mean * mean;
    float rstd = rsqrtf(fmaxf(var, 0.f) + 1e-12f);
#pragma unroll
    for (int j = 0; j < 4; j++) {
        float4 g  = *(const float4*)&gamma[j * 256 + lane * 4];
        float4 bt = *(const float4*)&beta [j * 256 + lane * 4];
        float4 o;
        o.x = g.x * (v[j * 4 + 0] - mean) * rstd + bt.x;
        o.y = g.y * (v[j * 4 + 1] - mean) * rstd + bt.y;
        o.z = g.z * (v[j * 4 + 2] - mean) * rstd + bt.z;
        o.w = g.w * (v[j * 4 + 3] - mean) * rstd + bt.w;
        *(float4*)&rp[j * 256 + lane * 4] = o;
    }
}

// ---------------------------------------------------------------------------
extern "C" void kernel_launch(void* const* d_in, const int* in_sizes, int n_in,
                              void* d_out, int out_size, void* d_ws, size_t ws_size,
                              hipStream_t stream) {
    const float* x     = (const float*)d_in[0];
    const float* Wq    = (const float*)d_in[2];
    const float* bq    = (const float*)d_in[3];
    const float* Wk    = (const float*)d_in[4];
    const float* bk    = (const float*)d_in[5];
    const float* Wv    = (const float*)d_in[6];
    const float* bv    = (const float*)d_in[7];
    const float* Wd    = (const float*)d_in[8];
    const float* bd    = (const float*)d_in[9];
    const float* gamma = (const float*)d_in[10];
    const float* beta  = (const float*)d_in[11];
    float* out = (float*)d_out;

    // Workspace:
    //   [0, 16.78M)        qkp  [16384][512] bf16
    //   [16.78M, 50.33M)   ut   [8][1024][2048] bf16
    //   [50.33M, 83.89M)   P    [4][2048][2048] bf16  (group-local, reused)
    //       aliases: x16 @ 50.33M (dead after proj2)
    //   [83.89M, ...)      Wv16, Wvdt, Wdt, Wqkt (dead after proj2)
    //   [117.44M, ..)      lg (64K), bc (4K), bqk (2K)
    char* ws = (char*)d_ws;
    u16*   qkp  = (u16*)(ws + 0);
    u16*   ut   = (u16*)(ws + 16777216);
    u16*   P    = (u16*)(ws + 50331648);
    u16*   x16  = (u16*)(ws + 50331648);
    u16*   Wv16 = (u16*)(ws + 83886080);
    u16*   Wvdt = (u16*)(ws + 85983232);
    u16*   Wdt  = (u16*)(ws + 88080384);
    u16*   Wqkt = (u16*)(ws + 90177536);
    float* lg   = (float*)(ws + 117440512);
    float* bc   = (float*)(ws + 117506048);
    float* bqk  = (float*)(ws + 117510144);

    k_cast_bf16<<<dim3(16384), dim3(256), 0, stream>>>(x, x16);
    k_prep<<<dim3(32, 32, 5), dim3(256), 0, stream>>>(Wq, Wk, Wv, Wd, bv, bd, bq, bk,
                                                      Wqkt, Wv16, Wdt, bc, bqk);
    k_gemm64<<<dim3(16, 16), dim3(256), 0, stream>>>(Wv16, Wdt, Wvdt, 1024);

    k_proj2<<<dim3(64, 6), dim3(512), 0, stream>>>(x16, Wqkt, Wvdt, bqk, qkp, ut);

    hipMemsetAsync(lg, 0, (size_t)BB * SS * sizeof(float), stream);

    for (int g = 0; g < 2; g++) {
        const size_t qo = (size_t)g * 4 * SS * 512;
        const size_t uo = (size_t)g * 4 * (size_t)DD * SS;
        const size_t xo = (size_t)g * 4 * (size_t)SS * DD;
        const size_t lo = (size_t)g * 4 * SS;
        k_qk2<<<dim3(8, 8, 4), dim3(512), 0, stream>>>(qkp + qo, P, lg + lo);
        k_h3 <<<dim3(8, 8, 4), dim3(512), 0, stream>>>(P, ut + uo, lg + lo, bc, x + xo, out + xo);
    }

    k_ln_f32<<<dim3(4096), dim3(256), 0, stream>>>(out, gamma, beta);
}

// Round 4
// 358.390 us; speedup vs baseline: 1.1957x; 1.0395x over previous
//
#include <hip/hip_runtime.h>
#include <stdint.h>

#define BB 8
#define SS 2048
#define DD 1024
#define KREAL 204

typedef __attribute__((ext_vector_type(8))) short short8;
typedef __attribute__((ext_vector_type(4))) float floatx4;
typedef uint16_t u16;
typedef uint32_t u32;

__device__ __forceinline__ float bf2f(u16 u) {
    union { float f; u32 i; } c; c.i = ((u32)u) << 16; return c.f;
}
__device__ __forceinline__ u16 f2bf(float f) {
    union { float f; u32 i; } c; c.f = f;
    u32 i = c.i;
    u32 r = (i + 0x7FFFu + ((i >> 16) & 1u)) >> 16;
    return (u16)r;
}

#if defined(__has_builtin)
#if __has_builtin(__builtin_amdgcn_global_load_lds)
#define HAVE_GLL 1
#endif
#endif

__device__ __forceinline__ void gload16(const u16* g, u16* l) {
#ifdef HAVE_GLL
    __builtin_amdgcn_global_load_lds(
        (const __attribute__((address_space(1))) void*)(uintptr_t)g,
        (__attribute__((address_space(3))) void*)(u32)(uintptr_t)(void*)l,
        16, 0, 0);
#else
    *(uint4*)l = *(const uint4*)g;
#endif
}

#define VM_WAIT(N) asm volatile("s_waitcnt vmcnt(" #N ")" ::: "memory")
#define S_BAR()    asm volatile("s_barrier" ::: "memory")

// ===========================================================================
// Legacy 64-wide-row swizzled staging (kept for k_gemm64 only).
// ===========================================================================
__device__ __forceinline__ void stage64(const u16* __restrict__ src, size_t ld,
                                        u16* lds, int tid) {
#pragma unroll
    for (int j = 0; j < 2; j++) {
        int flat = j * 256 + tid;
        int row = flat >> 3, slot = flat & 7;
        int kg = slot ^ (row & 7);
        gload16(src + (size_t)row * ld + kg * 8, lds + flat * 8);
    }
}
__device__ __forceinline__ short8 frag(const u16* lds, int row, int kslot) {
    return *(const short8*)&lds[(row << 6) + (((kslot ^ (row & 7)) & 7) << 3)];
}

// ===========================================================================
// 256x256 8-wave GEMM core, RING-5 half-tile pipeline (full 160 KiB LDS:
// 5 A-slots + 5 B-slots of 16 KB). BK=64 as two K-half planes of 32.
// Staging via global_load_lds with pre-swizzled SOURCE (kg = slot ^
// ((row>>1)&3)); frag reads apply the matching XOR -> max 2-way bank
// aliasing (free; SQ_LDS_BANK_CONFLICT == 0 verified rounds 1-3).
//
// Half-tile h = 2t+k lives in slot h%5; staged exactly 2 tiles ahead.
// Counted-vmcnt (4 loads per half-tile), never drains in the main loop:
//   tile t: VM(12); BAR; SH(2t+4 -> slot (2t+4)%5 = t-1's k1 slot, released
//           by this barrier); phases k0 (slot 2t%5);
//           VM(12); BAR; SH(2t+5 -> slot 2t%5, released by this barrier);
//           phases k1 (slot (2t+1)%5).
// Exact tail counts (no guards needed; main loop stops at NT-3):
//   t=NT-2: VM(12)/VM(8);  t=NT-1: VM(4)/VM(0).
// Wait proof: at tile-t top, loads newer than S(2t) are exactly
// {S(2t+1),S(2t+2),S(2t+3)} = 12; mid, newer than S(2t+1) are 12. ✓
// ===========================================================================
__device__ __forceinline__ short8 frag32(const u16* plane, int row, int ks) {
    return *(const short8*)&plane[(row << 5) + (((ks ^ ((row >> 1) & 3)) & 3) << 3)];
}

template <int MT0, bool LOADB>
__device__ __forceinline__ void phase16(const u16* Apl, const u16* Bpl,
                                        int arow, int brow, int ln, int quad,
                                        short8 (&bv)[4], floatx4 (&acc)[8][4]) {
    short8 af[4];
#pragma unroll
    for (int i = 0; i < 4; i++) af[i] = frag32(Apl, arow + (MT0 + i) * 16 + ln, quad);
    if (LOADB) {
#pragma unroll
        for (int nt = 0; nt < 4; nt++) bv[nt] = frag32(Bpl, brow + nt * 16 + ln, quad);
    }
    __builtin_amdgcn_s_setprio(1);
#pragma unroll
    for (int i = 0; i < 4; i++)
#pragma unroll
        for (int nt = 0; nt < 4; nt++)
            acc[MT0 + i][nt] = __builtin_amdgcn_mfma_f32_16x16x32_bf16(
                af[i], bv[nt], acc[MT0 + i][nt], 0, 0, 0);
    __builtin_amdgcn_s_setprio(0);
}

template <int NT>
__device__ __forceinline__ void gemm_core5(
    const u16* __restrict__ Ag, size_t lda,
    const u16* __restrict__ Bg, size_t ldb,
    u16* lds, int tid, floatx4 (&acc)[8][4]) {
    static_assert(NT >= 3, "ring-5 core needs NT >= 3");
    const int lane = tid & 63, w = tid >> 6;
    const int arow = (w >> 2) * 128, brow = (w & 3) * 64;
    const int ln = lane & 15, quad = lane >> 4;
    const int srow = tid >> 2;
    const int kgp = (tid & 3) ^ ((srow >> 1) & 3);
    const u16* A0 = Ag + (size_t)srow * lda + kgp * 8;
    const u16* A1 = Ag + (size_t)(srow + 128) * lda + kgp * 8;
    const u16* B0 = Bg + (size_t)srow * ldb + kgp * 8;
    const u16* B1 = Bg + (size_t)(srow + 128) * ldb + kgp * 8;
    u16* Al = lds;
    u16* Bl = lds + 5 * 8192;

    auto SH = [&](int sl, int h) {   // stage half-tile h -> slot sl (4 loads)
        size_t koff = (size_t)h * 32;
        gload16(A0 + koff, Al + sl * 8192 + tid * 8);
        gload16(A1 + koff, Al + sl * 8192 + 4096 + tid * 8);
        gload16(B0 + koff, Bl + sl * 8192 + tid * 8);
        gload16(B1 + koff, Bl + sl * 8192 + 4096 + tid * 8);
    };

    SH(0, 0); SH(1, 1); SH(2, 2); SH(3, 3);   // 16 loads

    short8 bv[4];
    int sl0 = 0, sl1 = 1;
#pragma unroll 2
    for (int t = 0; t < NT - 2; ++t) {
        const u16* Ap0 = Al + sl0 * 8192;  const u16* Bp0 = Bl + sl0 * 8192;
        const u16* Ap1 = Al + sl1 * 8192;  const u16* Bp1 = Bl + sl1 * 8192;
        const int st = sl0 ? sl0 - 1 : 4;          // (2t+4)%5
        VM_WAIT(12); S_BAR();
        SH(st, 2 * t + 4);
        phase16<0, true >(Ap0, Bp0, arow, brow, ln, quad, bv, acc);
        phase16<4, false>(Ap0, Bp0, arow, brow, ln, quad, bv, acc);
        VM_WAIT(12); S_BAR();
        SH(sl0, 2 * t + 5);                        // (2t+5)%5 == sl0
        phase16<0, true >(Ap1, Bp1, arow, brow, ln, quad, bv, acc);
        phase16<4, false>(Ap1, Bp1, arow, brow, ln, quad, bv, acc);
        sl0 += 2; if (sl0 >= 5) sl0 -= 5;
        sl1 += 2; if (sl1 >= 5) sl1 -= 5;
    }
    {   // t = NT-2: newer-than-needed = 12 (top) / 8 (mid)
        const u16* Ap0 = Al + sl0 * 8192;  const u16* Bp0 = Bl + sl0 * 8192;
        const u16* Ap1 = Al + sl1 * 8192;  const u16* Bp1 = Bl + sl1 * 8192;
        VM_WAIT(12); S_BAR();
        phase16<0, true >(Ap0, Bp0, arow, brow, ln, quad, bv, acc);
        phase16<4, false>(Ap0, Bp0, arow, brow, ln, quad, bv, acc);
        VM_WAIT(8); S_BAR();
        phase16<0, true >(Ap1, Bp1, arow, brow, ln, quad, bv, acc);
        phase16<4, false>(Ap1, Bp1, arow, brow, ln, quad, bv, acc);
        sl0 += 2; if (sl0 >= 5) sl0 -= 5;
        sl1 += 2; if (sl1 >= 5) sl1 -= 5;
    }
    {   // t = NT-1: newer = 4 (top) / 0 (mid)
        const u16* Ap0 = Al + sl0 * 8192;  const u16* Bp0 = Bl + sl0 * 8192;
        const u16* Ap1 = Al + sl1 * 8192;  const u16* Bp1 = Bl + sl1 * 8192;
        VM_WAIT(4); S_BAR();
        phase16<0, true >(Ap0, Bp0, arow, brow, ln, quad, bv, acc);
        phase16<4, false>(Ap0, Bp0, arow, brow, ln, quad, bv, acc);
        VM_WAIT(0); S_BAR();
        phase16<0, true >(Ap1, Bp1, arow, brow, ln, quad, bv, acc);
        phase16<4, false>(Ap1, Bp1, arow, brow, ln, quad, bv, acc);
    }
}

// ===========================================================================
// Epilogue stores for the 256x256 tile (LDS bounce -> contiguous dwordx4).
// ===========================================================================
template <typename F>
__device__ __forceinline__ void store_rm256(u16* smem, u16* gbase, size_t ldc,
                                            int wm, int wn, int ln, int quad,
                                            int tid, F val) {
    for (int half = 0; half < 2; half++) {
        __syncthreads();
        if (wm == half) {
#pragma unroll
            for (int mt = 0; mt < 8; mt++)
#pragma unroll
                for (int nt = 0; nt < 4; nt++)
#pragma unroll
                    for (int r = 0; r < 4; r++)
                        smem[(mt * 16 + quad * 4 + r) * 264 + wn * 64 + nt * 16 + ln] =
                            val(mt, nt, r);
        }
        __syncthreads();
#pragma unroll
        for (int j = 0; j < 8; j++) {
            int flat = j * 512 + tid;
            int row = flat >> 5, c = flat & 31;
            *(uint4*)&gbase[(size_t)(half * 128 + row) * ldc + c * 8] =
                *(const uint4*)&smem[row * 264 + c * 8];
        }
    }
}

template <typename F4>
__device__ __forceinline__ void store_tr256(u16* smem, u16* gbase, size_t ldg,
                                            int wm, int wn, int ln, int quad,
                                            int tid, F4 val4) {
    for (int qr = 0; qr < 4; qr++) {
        __syncthreads();
        if (wn == qr) {
#pragma unroll
            for (int mt = 0; mt < 8; mt++)
#pragma unroll
                for (int nt = 0; nt < 4; nt++) {
                    ushort4 v = val4(mt, nt);
                    *(ushort4*)&smem[(nt * 16 + ln) * 264 + wm * 128 + mt * 16 + quad * 4] = v;
                }
        }
        __syncthreads();
#pragma unroll
        for (int j = 0; j < 4; j++) {
            int flat = j * 512 + tid;
            int c = flat >> 5, r8 = flat & 31;
            *(uint4*)&gbase[(size_t)(qr * 64 + c) * ldg + r8 * 8] =
                *(const uint4*)&smem[c * 264 + r8 * 8];
        }
    }
}

// ===========================================================================
// Cast f32 -> bf16.
// ===========================================================================
__global__ __launch_bounds__(256) void k_cast_bf16(
    const float* __restrict__ x, u16* __restrict__ o) {
    size_t i = ((size_t)blockIdx.x * 256 + threadIdx.x) * 4;
    float4 v = *(const float4*)&x[i];
    ushort4 p;
    p.x = f2bf(v.x); p.y = f2bf(v.y); p.z = f2bf(v.z); p.w = f2bf(v.w);
    *(ushort4*)&o[i] = p;
}

// ---------------------------------------------------------------------------
// Prep (one launch): z=0 Wq->Wqkt rows 0-255, z=1 Wk->Wqkt rows 256-511,
// z=2 Wv cast -> Wv16, z=3 Wd->Wdt, z=4 bias prep.
// ---------------------------------------------------------------------------
__global__ __launch_bounds__(256) void k_prep(
    const float* __restrict__ Wq, const float* __restrict__ Wk,
    const float* __restrict__ Wv, const float* __restrict__ Wd,
    const float* __restrict__ bv, const float* __restrict__ bd,
    const float* __restrict__ bq, const float* __restrict__ bk,
    u16* __restrict__ Wqkt, u16* __restrict__ Wv16, u16* __restrict__ Wdt,
    float* __restrict__ bc, float* __restrict__ bqk) {
    const int z = blockIdx.z;
    const int t = threadIdx.x;
    if (z == 4) {
        int id = blockIdx.y * 32 + blockIdx.x;
        if (id < 16) {
            __shared__ float red[4][64];
            int n = id * 64 + (t & 63);
            int dc = t >> 6;
            float s = 0.f;
            for (int d = dc * 256; d < dc * 256 + 256; d++)
                s += bv[d] * Wd[(size_t)d * 1024 + n];
            red[dc][t & 63] = s;
            __syncthreads();
            if (dc == 0) bc[n] = bd[n] + red[0][t & 63] + red[1][t & 63] + red[2][t & 63] + red[3][t & 63];
        } else if (id == 16) {
            for (int i = t; i < 512; i += 256) {
                float v = 0.f;
                if (i < KREAL) v = bq[i];
                else if (i >= 256 && i < 256 + KREAL) v = bk[i - 256];
                bqk[i] = v;
            }
        }
        return;
    }
    __shared__ u16 tile[32][33];
    int k0 = blockIdx.x * 32, n0 = blockIdx.y * 32;
    int tx = t & 31, ty = t >> 5;
    if (z == 2) {
        for (int i = ty; i < 32; i += 8) {
            size_t idx = (size_t)(k0 + i) * 1024 + n0 + tx;
            Wv16[idx] = f2bf(Wv[idx]);
        }
        return;
    }
    const float* W; u16* out; int N, Npad, rowoff;
    if (z == 0)      { W = Wq; out = Wqkt; N = KREAL; Npad = 256;  rowoff = 0;   }
    else if (z == 1) { W = Wk; out = Wqkt; N = KREAL; Npad = 256;  rowoff = 256; }
    else             { W = Wd; out = Wdt;  N = 1024;  Npad = 1024; rowoff = 0;   }
    if (n0 >= Npad) return;
    for (int i = ty; i < 32; i += 8) {
        int n = n0 + tx;
        tile[i][tx] = (n < N) ? f2bf(W[(size_t)(k0 + i) * N + n]) : (u16)0;
    }
    __syncthreads();
    for (int i = ty; i < 32; i += 8) {
        int n = n0 + i;
        if (n < Npad) out[(size_t)(rowoff + n) * 1024 + k0 + tx] = tile[tx][i];
    }
}

// ---------------------------------------------------------------------------
// Small GEMM (64x64 tiles): Wvdt[j][i] = sum_k Wv[i][k]*Wd[k][j].
// ---------------------------------------------------------------------------
__global__ __launch_bounds__(256) void k_gemm64(
    const u16* __restrict__ A, const u16* __restrict__ Bt,
    u16* __restrict__ C, int ldc) {
    __shared__ u16 As[64 * 64];
    __shared__ u16 Bs[64 * 64];
    const int tid = threadIdx.x;
    const int m0 = blockIdx.x * 64, n0 = blockIdx.y * 64;
    const int lane = tid & 63, w = tid >> 6;
    const int ln = lane & 15, quad = lane >> 4;

    floatx4 acc[4];
    floatx4 zero = {0.f, 0.f, 0.f, 0.f};
#pragma unroll
    for (int nt = 0; nt < 4; nt++) acc[nt] = zero;

    for (int kt = 0; kt < 16; kt++) {
        __syncthreads();
        stage64(A + (size_t)m0 * 1024 + kt * 64, 1024, As, tid);
        stage64(Bt + (size_t)n0 * 1024 + kt * 64, 1024, Bs, tid);
        __syncthreads();
#pragma unroll
        for (int kk = 0; kk < 2; kk++) {
            short8 av = frag(As, w * 16 + ln, kk * 4 + quad);
#pragma unroll
            for (int nt = 0; nt < 4; nt++) {
                short8 bvf = frag(Bs, nt * 16 + ln, kk * 4 + quad);
                acc[nt] = __builtin_amdgcn_mfma_f32_16x16x32_bf16(av, bvf, acc[nt], 0, 0, 0);
            }
        }
    }
    const int row0 = m0 + w * 16 + quad * 4;
#pragma unroll
    for (int nt = 0; nt < 4; nt++) {
        const int col = n0 + nt * 16 + ln;
        ushort4 pk;
        pk.x = f2bf(acc[nt][0]); pk.y = f2bf(acc[nt][1]);
        pk.z = f2bf(acc[nt][2]); pk.w = f2bf(acc[nt][3]);
        *reinterpret_cast<ushort4*>(&C[(size_t)col * ldc + row0]) = pk;
    }
}

// ---------------------------------------------------------------------------
// Merged projection, 256x256 ring-5 core, identity mapping.
// grid (64, 6), 512 threads, 160 KiB LDS.
// ---------------------------------------------------------------------------
__global__ __launch_bounds__(512, 2) void k_proj2(
    const u16* __restrict__ A, const u16* __restrict__ Wqkt,
    const u16* __restrict__ Wvdt, const float* __restrict__ bqk,
    u16* __restrict__ qkp, u16* __restrict__ ut) {
    __shared__ __align__(16) u16 lds[81920];
    const int tid = threadIdx.x;
    const int m0 = blockIdx.x * 256;
    const int by = blockIdx.y;
    const int lane = tid & 63, w = tid >> 6;
    const int wm = w >> 2, wn = w & 3;
    const int ln = lane & 15, quad = lane >> 4;

    floatx4 acc[8][4];
    floatx4 zero = {0.f, 0.f, 0.f, 0.f};
#pragma unroll
    for (int mt = 0; mt < 8; mt++)
#pragma unroll
        for (int nt = 0; nt < 4; nt++) acc[mt][nt] = zero;

    const u16* Ag = A + (size_t)m0 * 1024;
    const int n0 = (by < 2) ? by * 256 : (by - 2) * 256;
    const u16* Bg = (by < 2) ? (Wqkt + (size_t)n0 * 1024) : (Wvdt + (size_t)n0 * 1024);
    gemm_core5<16>(Ag, 1024, Bg, 1024, lds, tid, acc);

    if (by < 2) {
        float b4[4];
#pragma unroll
        for (int nt = 0; nt < 4; nt++) b4[nt] = bqk[n0 + wn * 64 + nt * 16 + ln];
        store_rm256(lds, qkp + (size_t)m0 * 512 + n0, 512, wm, wn, ln, quad, tid,
            [&](int mt, int nt, int r) -> u16 {
                return f2bf(acc[mt][nt][r] + b4[nt]);
            });
    } else {
        int b = m0 >> 11, s0loc = m0 & 2047;
        store_tr256(lds, ut + ((size_t)b * DD + n0) * SS + s0loc, SS, wm, wn, ln, quad, tid,
            [&](int mt, int nt) -> ushort4 {
                ushort4 pk;
                pk.x = f2bf(acc[mt][nt][0]); pk.y = f2bf(acc[mt][nt][1]);
                pk.z = f2bf(acc[mt][nt][2]); pk.w = f2bf(acc[mt][nt][3]);
                return pk;
            });
    }
}

// ---------------------------------------------------------------------------
// QK GEMM (all 8 batches, one launch): P = bf16(exp(q.k - 30)); row sums via
// atomics. grid (8, 8, 8), 512 threads, identity mapping, ring-5 core.
// ---------------------------------------------------------------------------
__global__ __launch_bounds__(512, 2) void k_qk2(
    const u16* __restrict__ qkp, u16* __restrict__ P, float* __restrict__ lg) {
    __shared__ __align__(16) u16 lds[81920];
    const int tid = threadIdx.x;
    const int s0 = blockIdx.x * 256, t0 = blockIdx.y * 256, bb = blockIdx.z;
    const int lane = tid & 63, w = tid >> 6;
    const int wm = w >> 2, wn = w & 3;
    const int ln = lane & 15, quad = lane >> 4;

    floatx4 acc[8][4];
    floatx4 zero = {0.f, 0.f, 0.f, 0.f};
#pragma unroll
    for (int mt = 0; mt < 8; mt++)
#pragma unroll
        for (int nt = 0; nt < 4; nt++) acc[mt][nt] = zero;

    gemm_core5<4>(qkp + ((size_t)bb * SS + s0) * 512, 512,
                  qkp + ((size_t)bb * SS + t0) * 512 + 256, 512, lds, tid, acc);

#pragma unroll
    for (int mt = 0; mt < 8; mt++)
#pragma unroll
        for (int nt = 0; nt < 4; nt++)
#pragma unroll
            for (int r = 0; r < 4; r++)
                acc[mt][nt][r] = __expf(acc[mt][nt][r] - 30.f);

#pragma unroll
    for (int mt = 0; mt < 8; mt++) {
#pragma unroll
        for (int r = 0; r < 4; r++) {
            float rs = acc[mt][0][r] + acc[mt][1][r] + acc[mt][2][r] + acc[mt][3][r];
            rs += __shfl_xor(rs, 1);
            rs += __shfl_xor(rs, 2);
            rs += __shfl_xor(rs, 4);
            rs += __shfl_xor(rs, 8);
            if (ln == 0)
                atomicAdd(&lg[(size_t)bb * SS + s0 + wm * 128 + mt * 16 + quad * 4 + r], rs);
        }
    }

    store_rm256(lds, P + (size_t)bb * SS * SS + (size_t)s0 * SS + t0, SS,
                wm, wn, ln, quad, tid,
        [&](int mt, int nt, int r) -> u16 { return f2bf(acc[mt][nt][r]); });
}

// ---------------------------------------------------------------------------
// Final GEMM (all 8 batches, one launch): out = (P.ut)/l + bc + x  (f32,
// straight into d_out; LN runs in-place afterwards). Ring-5 core, NT=32.
// Epilogue: acc bounced through LDS; /l + bc + xres applied in the copy-out
// phase with fully-coalesced float4 traffic by all 512 threads.
// grid (8, 4, 8), 512 threads, identity mapping.
// ---------------------------------------------------------------------------
__global__ __launch_bounds__(512, 2) void k_h2(
    const u16* __restrict__ P, const u16* __restrict__ ut,
    const float* __restrict__ lg, const float* __restrict__ bc,
    const float* __restrict__ xres, float* __restrict__ out) {
    __shared__ __align__(16) u16 lds[81920];
    const int tid = threadIdx.x;
    const int s0 = blockIdx.x * 256, d0 = blockIdx.y * 256, bb = blockIdx.z;
    const int lane = tid & 63, w = tid >> 6;
    const int wm = w >> 2;
    const int ln = lane & 15, quad = lane >> 4;

    floatx4 acc[8][4];
    floatx4 zero = {0.f, 0.f, 0.f, 0.f};
#pragma unroll
    for (int mt = 0; mt < 8; mt++)
#pragma unroll
        for (int nt = 0; nt < 4; nt++) acc[mt][nt] = zero;

    gemm_core5<32>(P + ((size_t)bb * SS + s0) * SS, SS,
                   ut + ((size_t)bb * DD + d0) * SS, SS, lds, tid, acc);

    float* smem = (float*)lds;
    float* outb = out + ((size_t)bb * SS + s0) * DD + d0;
    const float* xb = xres + ((size_t)bb * SS + s0) * DD + d0;
    const float* lgb = lg + (size_t)bb * SS + s0;
    const int wn = w & 3;
    for (int c4 = 0; c4 < 4; c4++) {
        __syncthreads();
        if (wm == (c4 >> 1)) {
#pragma unroll
            for (int i = 0; i < 4; i++)
#pragma unroll
                for (int nt = 0; nt < 4; nt++)
#pragma unroll
                    for (int r = 0; r < 4; r++)
                        smem[(i * 16 + quad * 4 + r) * 260 + wn * 64 + nt * 16 + ln] =
                            acc[(c4 & 1) * 4 + i][nt][r];
        }
        __syncthreads();
#pragma unroll
        for (int j = 0; j < 8; j++) {
            int flat = j * 512 + tid;
            int row = flat >> 6, q = flat & 63;
            float iv = 1.f / lgb[c4 * 64 + row];
            float4 a  = *(const float4*)&smem[row * 260 + q * 4];
            float4 b4 = *(const float4*)&bc[d0 + q * 4];
            float4 xr = *(const float4*)&xb[(size_t)(c4 * 64 + row) * DD + q * 4];
            float4 o;
            o.x = a.x * iv + b4.x + xr.x;
            o.y = a.y * iv + b4.y + xr.y;
            o.z = a.z * iv + b4.z + xr.z;
            o.w = a.w * iv + b4.w + xr.w;
            *(float4*)&outb[(size_t)(c4 * 64 + row) * DD + q * 4] = o;
        }
    }
}

// ---------------------------------------------------------------------------
// LayerNorm over last dim (1024), f32 IN-PLACE on d_out. Each block owns 4
// rows exclusively -> no cross-block hazard.
// ---------------------------------------------------------------------------
__global__ __launch_bounds__(256) void k_ln_f32(
    float* __restrict__ io, const float* __restrict__ gamma,
    const float* __restrict__ beta) {
    const int tid = threadIdx.x;
    const int lane = tid & 63, w = tid >> 6;
    const size_t row = (size_t)blockIdx.x * 4 + w;
    float* rp = io + row * DD;

    float v[16];
#pragma unroll
    for (int j = 0; j < 4; j++) {
        float4 t = *(const float4*)&rp[j * 256 + lane * 4];
        v[j * 4 + 0] = t.x; v[j * 4 + 1] = t.y; v[j * 4 + 2] = t.z; v[j * 4 + 3] = t.w;
    }
    float s = 0.f, sq = 0.f;
#pragma unroll
    for (int i = 0; i < 16; i++) { s += v[i]; sq += v[i] * v[i]; }
#pragma unroll
    for (int msk = 1; msk < 64; msk <<= 1) {
        s  += __shfl_xor(s,  msk, 64);
        sq += __shfl_xor(sq, msk, 64);
    }
    float mean = s * (1.f / 1024.f);
    float var  = sq * (1.f / 1024.f) - mean * mean;
    float rstd = rsqrtf(fmaxf(var, 0.f) + 1e-12f);
#pragma unroll
    for (int j = 0; j < 4; j++) {
        float4 g  = *(const float4*)&gamma[j * 256 + lane * 4];
        float4 bt = *(const float4*)&beta [j * 256 + lane * 4];
        float4 o;
        o.x = g.x * (v[j * 4 + 0] - mean) * rstd + bt.x;
        o.y = g.y * (v[j * 4 + 1] - mean) * rstd + bt.y;
        o.z = g.z * (v[j * 4 + 2] - mean) * rstd + bt.z;
        o.w = g.w * (v[j * 4 + 3] - mean) * rstd + bt.w;
        *(float4*)&rp[j * 256 + lane * 4] = o;
    }
}

// ---------------------------------------------------------------------------
extern "C" void kernel_launch(void* const* d_in, const int* in_sizes, int n_in,
                              void* d_out, int out_size, void* d_ws, size_t ws_size,
                              hipStream_t stream) {
    const float* x     = (const float*)d_in[0];
    const float* Wq    = (const float*)d_in[2];
    const float* bq    = (const float*)d_in[3];
    const float* Wk    = (const float*)d_in[4];
    const float* bk    = (const float*)d_in[5];
    const float* Wv    = (const float*)d_in[6];
    const float* bv    = (const float*)d_in[7];
    const float* Wd    = (const float*)d_in[8];
    const float* bd    = (const float*)d_in[9];
    const float* gamma = (const float*)d_in[10];
    const float* beta  = (const float*)d_in[11];
    float* out = (float*)d_out;

    // Workspace (round-1 layout):
    //   [0, 16.78M)        qkp  [16384][512] bf16
    //   [16.78M, 50.33M)   ut   [8][1024][2048] bf16
    //   [50.33M, 117.44M)  P    [8][2048][2048] bf16
    //       aliases (dead before qk writes P):
    //         x16 @ 50.33M, Wv16 @ 83.89M, Wvdt @ 85.98M,
    //         Wdt @ 88.08M, Wqkt @ 90.18M
    //   [117.44M, ..)      lg (64K), bc (4K), bqk (2K)
    char* ws = (char*)d_ws;
    u16*   qkp  = (u16*)(ws + 0);
    u16*   ut   = (u16*)(ws + 16777216);
    u16*   P    = (u16*)(ws + 50331648);
    u16*   x16  = (u16*)(ws + 50331648);
    u16*   Wv16 = (u16*)(ws + 83886080);
    u16*   Wvdt = (u16*)(ws + 85983232);
    u16*   Wdt  = (u16*)(ws + 88080384);
    u16*   Wqkt = (u16*)(ws + 90177536);
    float* lg   = (float*)(ws + 117440512);
    float* bc   = (float*)(ws + 117506048);
    float* bqk  = (float*)(ws + 117510144);

    k_cast_bf16<<<dim3(16384), dim3(256), 0, stream>>>(x, x16);
    k_prep<<<dim3(32, 32, 5), dim3(256), 0, stream>>>(Wq, Wk, Wv, Wd, bv, bd, bq, bk,
                                                      Wqkt, Wv16, Wdt, bc, bqk);
    k_gemm64<<<dim3(16, 16), dim3(256), 0, stream>>>(Wv16, Wdt, Wvdt, 1024);

    k_proj2<<<dim3(64, 6), dim3(512), 0, stream>>>(x16, Wqkt, Wvdt, bqk, qkp, ut);

    hipMemsetAsync(lg, 0, (size_t)BB * SS * sizeof(float), stream);

    k_qk2<<<dim3(8, 8, 8), dim3(512), 0, stream>>>(qkp, P, lg);
    k_h2 <<<dim3(8, 4, 8), dim3(512), 0, stream>>>(P, ut, lg, bc, x, out);

    k_ln_f32<<<dim3(4096), dim3(256), 0, stream>>>(out, gamma, beta);
}